// Round 1
// baseline (308.644 us; speedup 1.0000x reference)
//
#include <hip/hip_runtime.h>

// ToRGBLayer modulated face-conv, MI355X (gfx950)
// out[n,o] = clip( sum_k sum_c x[nb[n,k],c] * weight[o,c,k] * styles[b,c], +-256 )
// styles[b,c] = (w[b,:] . affine_weight[c,:] / sqrt(512) + affine_bias[c]) / 32

#define N_FACES   393216   // B * F
#define C_IN      256
#define C_OUT     3
#define W_DIM     512
#define K2        4
#define BATCH     4
#define F_PER_B   98304

// ---------------------------------------------------------------------------
// Kernel 1: wmod[b][k][o][c] = weight[o][c][0][k] * styles[b][c]
// 1024 threads total (B * C_IN), each does one 512-dot then 12 writes.
// ---------------------------------------------------------------------------
__global__ __launch_bounds__(256) void wmod_kernel(
    const float* __restrict__ w,        // [B, W_DIM]
    const float* __restrict__ aw,       // [C_IN, W_DIM]
    const float* __restrict__ ab,       // [C_IN]
    const float* __restrict__ weight,   // [C_OUT, C_IN, 1, K2]
    float* __restrict__ wmod)           // [B, K2, C_OUT, C_IN]
{
    int t = blockIdx.x * blockDim.x + threadIdx.x;
    if (t >= BATCH * C_IN) return;
    int b = t >> 8;          // t / C_IN
    int c = t & 255;         // t % C_IN

    const float* wr = w  + b * W_DIM;
    const float* ar = aw + c * W_DIM;
    float acc = 0.f;
    #pragma unroll 4
    for (int d = 0; d < W_DIM; d += 4) {
        float4 wv = *reinterpret_cast<const float4*>(wr + d);
        float4 av = *reinterpret_cast<const float4*>(ar + d);
        acc += wv.x * av.x + wv.y * av.y + wv.z * av.z + wv.w * av.w;
    }
    const float rsqrt_wdim = 0.04419417382415922f;  // 1/sqrt(512)
    const float gain       = 0.03125f;              // 1/sqrt(C_IN*K2) = 1/32
    float s = (acc * rsqrt_wdim + ab[c]) * gain;

    #pragma unroll
    for (int o = 0; o < C_OUT; ++o)
        #pragma unroll
        for (int k = 0; k < K2; ++k)
            wmod[(((b * K2 + k) * C_OUT + o) << 8) + c] =
                weight[(o * C_IN + c) * K2 + k] * s;
}

// ---------------------------------------------------------------------------
// Kernel 2: one wave (64 lanes) per output face. Lane l owns channels
// [4l, 4l+4). Coalesced float4 gather of 4 neighbor rows, 48 FMAs/lane,
// then a 6-step shfl_xor wave reduction of 3 accumulators.
// ---------------------------------------------------------------------------
__global__ __launch_bounds__(256) void face_conv_kernel(
    const float* __restrict__ x,      // [N_FACES, C_IN]
    const int*   __restrict__ nb,     // [N_FACES, K2]
    const float* __restrict__ wmod,   // [B, K2, C_OUT, C_IN]
    const float* __restrict__ bias,   // [C_OUT]
    float*       __restrict__ out)    // [N_FACES, C_OUT]
{
    const int n    = (blockIdx.x * blockDim.x + threadIdx.x) >> 6;  // face id
    const int lane = threadIdx.x & 63;
    if (n >= N_FACES) return;
    const int b = n / F_PER_B;   // wave-uniform

    // neighbor indices (wave-uniform, single cacheline)
    const int4 idx4 = *reinterpret_cast<const int4*>(nb + n * K2);
    int idx[K2] = { idx4.x, idx4.y, idx4.z, idx4.w };

    const int cofs = lane << 2;  // this lane's channel offset
    const float* wm = wmod + ((b * K2 * C_OUT) << 8) + cofs;

    float acc0 = 0.f, acc1 = 0.f, acc2 = 0.f;
    #pragma unroll
    for (int k = 0; k < K2; ++k) {
        const int id = idx[k];
        if (id < N_FACES) {   // idx >= N_FACES -> pad slot -> contributes 0
            const float4 xv = *reinterpret_cast<const float4*>(x + id * C_IN + cofs);
            const float* wk = wm + ((k * C_OUT) << 8);
            const float4 w0 = *reinterpret_cast<const float4*>(wk);
            const float4 w1 = *reinterpret_cast<const float4*>(wk + 256);
            const float4 w2 = *reinterpret_cast<const float4*>(wk + 512);
            acc0 += xv.x * w0.x + xv.y * w0.y + xv.z * w0.z + xv.w * w0.w;
            acc1 += xv.x * w1.x + xv.y * w1.y + xv.z * w1.z + xv.w * w1.w;
            acc2 += xv.x * w2.x + xv.y * w2.y + xv.z * w2.z + xv.w * w2.w;
        }
    }

    // wave-wide reduction (64 lanes)
    #pragma unroll
    for (int off = 32; off > 0; off >>= 1) {
        acc0 += __shfl_xor(acc0, off, 64);
        acc1 += __shfl_xor(acc1, off, 64);
        acc2 += __shfl_xor(acc2, off, 64);
    }

    if (lane < C_OUT) {
        float v = (lane == 0) ? acc0 : (lane == 1) ? acc1 : acc2;
        v += bias[lane];
        v = fminf(fmaxf(v, -256.f), 256.f);
        out[n * C_OUT + lane] = v;
    }
}

// ---------------------------------------------------------------------------
extern "C" void kernel_launch(void* const* d_in, const int* in_sizes, int n_in,
                              void* d_out, int out_size, void* d_ws, size_t ws_size,
                              hipStream_t stream)
{
    const float* x      = (const float*)d_in[0];  // [N, C_IN]
    const int*   nb     = (const int*)  d_in[1];  // [N, K2]
    // d_in[2] = face_is_pad (structurally: pad iff slot >= N) -- unused
    // d_in[3] = pad_size scalar -- unused
    const float* w      = (const float*)d_in[4];  // [B, W_DIM]
    const float* aw     = (const float*)d_in[5];  // [C_IN, W_DIM]
    const float* ab     = (const float*)d_in[6];  // [C_IN]
    const float* weight = (const float*)d_in[7];  // [C_OUT, C_IN, 1, K2]
    const float* bias   = (const float*)d_in[8];  // [C_OUT]
    float*       out    = (float*)d_out;

    float* wmod = (float*)d_ws;  // B*K2*C_OUT*C_IN floats = 48 KB

    wmod_kernel<<<(BATCH * C_IN + 255) / 256, 256, 0, stream>>>(
        w, aw, ab, weight, wmod);

    const int waves_per_block = 256 / 64;
    const int grid = N_FACES / waves_per_block;  // 98304 blocks
    face_conv_kernel<<<grid, 256, 0, stream>>>(x, nb, wmod, bias, out);
}

// Round 2
// 140.720 us; speedup vs baseline: 2.1933x; 2.1933x over previous
//
#include <hip/hip_runtime.h>

// ToRGBLayer modulated face-conv, MI355X (gfx950) — factorized 2-pass version
// z[i,b,k,o] = sum_c x[i,c] * weight[o,c,k] * styles[b,c]   (streaming MFMA GEMM)
// out[n,o]   = clip( sum_k z[nb[n,k], b(n), k, o] + bias[o], +-256 )  (tiny gather)

#define N_FACES   393216   // B * F
#define C_IN      256
#define C_OUT     3
#define W_DIM     512
#define K2        4
#define BATCH     4
#define F_PER_B   98304
#define NJ        48       // BATCH * K2 * C_OUT

typedef __attribute__((ext_vector_type(8))) short bf16x8;
typedef __attribute__((ext_vector_type(4))) float f32x4;

static __device__ __forceinline__ unsigned short f2bf(float f) {
    union { float f; unsigned int u; } v; v.f = f;
    unsigned int r = v.u + 0x7FFFu + ((v.u >> 16) & 1u);   // RNE
    return (unsigned short)(r >> 16);
}
static __device__ __forceinline__ float bf2f(unsigned short u) {
    union { unsigned int u; float f; } v; v.u = ((unsigned int)u) << 16;
    return v.f;
}

// ---------------------------------------------------------------------------
// Kernel 1: wmodT[j][c] (bf16, j = b*12 + k*3 + o) = weight[o,c,0,k]*styles[b,c]
// ---------------------------------------------------------------------------
__global__ __launch_bounds__(256) void wmod_bf16_kernel(
    const float* __restrict__ w,        // [B, W_DIM]
    const float* __restrict__ aw,       // [C_IN, W_DIM]
    const float* __restrict__ ab,       // [C_IN]
    const float* __restrict__ weight,   // [C_OUT, C_IN, 1, K2]
    unsigned short* __restrict__ wmodT) // [NJ, C_IN] bf16
{
    int t = blockIdx.x * blockDim.x + threadIdx.x;
    if (t >= BATCH * C_IN) return;
    int b = t >> 8;
    int c = t & 255;

    const float* wr = w  + b * W_DIM;
    const float* ar = aw + c * W_DIM;
    float acc = 0.f;
    #pragma unroll 4
    for (int d = 0; d < W_DIM; d += 4) {
        float4 wv = *reinterpret_cast<const float4*>(wr + d);
        float4 av = *reinterpret_cast<const float4*>(ar + d);
        acc += wv.x * av.x + wv.y * av.y + wv.z * av.z + wv.w * av.w;
    }
    const float rsqrt_wdim = 0.04419417382415922f;  // 1/sqrt(512)
    const float gain       = 0.03125f;              // 1/sqrt(C_IN*K2)
    float s = (acc * rsqrt_wdim + ab[c]) * gain;

    #pragma unroll
    for (int o = 0; o < C_OUT; ++o)
        #pragma unroll
        for (int k = 0; k < K2; ++k) {
            int j = b * (K2 * C_OUT) + k * C_OUT + o;
            wmodT[j * C_IN + c] = f2bf(weight[(o * C_IN + c) * K2 + k] * s);
        }
}

// ---------------------------------------------------------------------------
// Kernel 2 (pass 1): z[i][j] = sum_c x[i][c] * wmodT[j][c], bf16 out.
// One wave per 16-face tile. 3 j-tiles of 16, K=256 in 8 steps of 32.
// mfma_f32_16x16x32_bf16: A lane l -> row l&15, k (l>>4)*8+e ;
// B lane l -> col l&15, k (l>>4)*8+e ; C/D lane l reg r -> row (l>>4)*4+r, col l&15.
// ---------------------------------------------------------------------------
#define LDW (C_IN + 8)   // padded LDS row: 264 ushort = 528 B (132 dw % 32 = 4 -> 2-way, free)

__global__ __launch_bounds__(256) void gemm_z_kernel(
    const float*          __restrict__ x,      // [N_FACES, C_IN]
    const unsigned short* __restrict__ wmodT,  // [NJ, C_IN] bf16
    unsigned short*       __restrict__ z)      // [N_FACES, NJ] bf16
{
    __shared__ unsigned short bs[NJ][LDW];

    // stage wmodT (48x256 bf16 = 24 KB) into padded LDS
    const unsigned int* g = reinterpret_cast<const unsigned int*>(wmodT);
    for (int i = threadIdx.x; i < NJ * (C_IN / 2); i += 256) {
        int r = i >> 7;          // /128 dwords per row
        int c = i & 127;
        reinterpret_cast<unsigned int*>(&bs[r][0])[c] = g[r * 128 + c];
    }
    __syncthreads();

    const int tile = (blockIdx.x * 256 + threadIdx.x) >> 6;   // 16-face tile id
    const int lane = threadIdx.x & 63;
    const int row  = lane & 15;
    const int kq   = lane >> 4;    // 0..3

    const float* xrow = x + (size_t)(tile * 16 + row) * C_IN + kq * 8;

    f32x4 acc0 = {0.f, 0.f, 0.f, 0.f};
    f32x4 acc1 = {0.f, 0.f, 0.f, 0.f};
    f32x4 acc2 = {0.f, 0.f, 0.f, 0.f};

    #pragma unroll
    for (int ks = 0; ks < 8; ++ks) {
        const float4* p = reinterpret_cast<const float4*>(xrow + ks * 32);
        float4 a0 = p[0];
        float4 a1 = p[1];
        union { bf16x8 v; unsigned short u[8]; } af;
        af.u[0] = f2bf(a0.x); af.u[1] = f2bf(a0.y);
        af.u[2] = f2bf(a0.z); af.u[3] = f2bf(a0.w);
        af.u[4] = f2bf(a1.x); af.u[5] = f2bf(a1.y);
        af.u[6] = f2bf(a1.z); af.u[7] = f2bf(a1.w);

        const int cofs = ks * 32 + kq * 8;
        bf16x8 b0 = *reinterpret_cast<const bf16x8*>(&bs[ 0 + row][cofs]);
        bf16x8 b1 = *reinterpret_cast<const bf16x8*>(&bs[16 + row][cofs]);
        bf16x8 b2 = *reinterpret_cast<const bf16x8*>(&bs[32 + row][cofs]);

        acc0 = __builtin_amdgcn_mfma_f32_16x16x32_bf16(af.v, b0, acc0, 0, 0, 0);
        acc1 = __builtin_amdgcn_mfma_f32_16x16x32_bf16(af.v, b1, acc1, 0, 0, 0);
        acc2 = __builtin_amdgcn_mfma_f32_16x16x32_bf16(af.v, b2, acc2, 0, 0, 0);
    }

    // store: lane l reg r -> face row (l>>4)*4+r, j col (l&15) + 16*jt
    const int colj  = lane & 15;
    const int rbase = tile * 16 + kq * 4;
    #pragma unroll
    for (int r = 0; r < 4; ++r) {
        size_t zr = (size_t)(rbase + r) * NJ;
        z[zr +  0 + colj] = f2bf(acc0[r]);
        z[zr + 16 + colj] = f2bf(acc1[r]);
        z[zr + 32 + colj] = f2bf(acc2[r]);
    }
}

// ---------------------------------------------------------------------------
// Kernel 3 (pass 2): out[n,o] = clip( sum_k z[idx[n,k]][b*12+k*3+o] + bias[o] )
// ---------------------------------------------------------------------------
__global__ __launch_bounds__(256) void gather_out_kernel(
    const int*            __restrict__ nb,    // [N_FACES, K2]
    const unsigned short* __restrict__ z,     // [N_FACES, NJ] bf16
    const float*          __restrict__ bias,  // [C_OUT]
    float*                __restrict__ out)   // [N_FACES, C_OUT]
{
    int n = blockIdx.x * 256 + threadIdx.x;
    if (n >= N_FACES) return;
    int b = n / F_PER_B;

    const int4 idx4 = *reinterpret_cast<const int4*>(nb + n * K2);
    int ids[K2] = { idx4.x, idx4.y, idx4.z, idx4.w };

    float s0 = 0.f, s1 = 0.f, s2 = 0.f;
    #pragma unroll
    for (int k = 0; k < K2; ++k) {
        int id = ids[k];
        if (id < N_FACES) {
            const unsigned short* p = z + (size_t)id * NJ + b * 12 + k * 3;
            s0 += bf2f(p[0]);
            s1 += bf2f(p[1]);
            s2 += bf2f(p[2]);
        }
    }
    s0 = fminf(fmaxf(s0 + bias[0], -256.f), 256.f);
    s1 = fminf(fmaxf(s1 + bias[1], -256.f), 256.f);
    s2 = fminf(fmaxf(s2 + bias[2], -256.f), 256.f);
    float* po = out + (size_t)n * C_OUT;
    po[0] = s0; po[1] = s1; po[2] = s2;
}

// ===========================================================================
// Fallback (round-1 verified direct path) — used only if ws_size is too small
// ===========================================================================
__global__ __launch_bounds__(256) void wmod_kernel(
    const float* __restrict__ w, const float* __restrict__ aw,
    const float* __restrict__ ab, const float* __restrict__ weight,
    float* __restrict__ wmod)
{
    int t = blockIdx.x * blockDim.x + threadIdx.x;
    if (t >= BATCH * C_IN) return;
    int b = t >> 8, c = t & 255;
    const float* wr = w + b * W_DIM;
    const float* ar = aw + c * W_DIM;
    float acc = 0.f;
    #pragma unroll 4
    for (int d = 0; d < W_DIM; d += 4) {
        float4 wv = *reinterpret_cast<const float4*>(wr + d);
        float4 av = *reinterpret_cast<const float4*>(ar + d);
        acc += wv.x * av.x + wv.y * av.y + wv.z * av.z + wv.w * av.w;
    }
    float s = (acc * 0.04419417382415922f + ab[c]) * 0.03125f;
    #pragma unroll
    for (int o = 0; o < C_OUT; ++o)
        #pragma unroll
        for (int k = 0; k < K2; ++k)
            wmod[(((b * K2 + k) * C_OUT + o) << 8) + c] =
                weight[(o * C_IN + c) * K2 + k] * s;
}

__global__ __launch_bounds__(256) void face_conv_kernel(
    const float* __restrict__ x, const int* __restrict__ nb,
    const float* __restrict__ wmod, const float* __restrict__ bias,
    float* __restrict__ out)
{
    const int n    = (blockIdx.x * blockDim.x + threadIdx.x) >> 6;
    const int lane = threadIdx.x & 63;
    if (n >= N_FACES) return;
    const int b = n / F_PER_B;
    const int4 idx4 = *reinterpret_cast<const int4*>(nb + n * K2);
    int idx[K2] = { idx4.x, idx4.y, idx4.z, idx4.w };
    const int cofs = lane << 2;
    const float* wm = wmod + ((b * K2 * C_OUT) << 8) + cofs;
    float acc0 = 0.f, acc1 = 0.f, acc2 = 0.f;
    #pragma unroll
    for (int k = 0; k < K2; ++k) {
        const int id = idx[k];
        if (id < N_FACES) {
            const float4 xv = *reinterpret_cast<const float4*>(x + (size_t)id * C_IN + cofs);
            const float* wk = wm + ((k * C_OUT) << 8);
            const float4 w0 = *reinterpret_cast<const float4*>(wk);
            const float4 w1 = *reinterpret_cast<const float4*>(wk + 256);
            const float4 w2 = *reinterpret_cast<const float4*>(wk + 512);
            acc0 += xv.x * w0.x + xv.y * w0.y + xv.z * w0.z + xv.w * w0.w;
            acc1 += xv.x * w1.x + xv.y * w1.y + xv.z * w1.z + xv.w * w1.w;
            acc2 += xv.x * w2.x + xv.y * w2.y + xv.z * w2.z + xv.w * w2.w;
        }
    }
    #pragma unroll
    for (int off = 32; off > 0; off >>= 1) {
        acc0 += __shfl_xor(acc0, off, 64);
        acc1 += __shfl_xor(acc1, off, 64);
        acc2 += __shfl_xor(acc2, off, 64);
    }
    if (lane < C_OUT) {
        float v = (lane == 0) ? acc0 : (lane == 1) ? acc1 : acc2;
        v += bias[lane];
        v = fminf(fmaxf(v, -256.f), 256.f);
        out[n * C_OUT + lane] = v;
    }
}

// ---------------------------------------------------------------------------
extern "C" void kernel_launch(void* const* d_in, const int* in_sizes, int n_in,
                              void* d_out, int out_size, void* d_ws, size_t ws_size,
                              hipStream_t stream)
{
    const float* x      = (const float*)d_in[0];
    const int*   nb     = (const int*)  d_in[1];
    const float* w      = (const float*)d_in[4];
    const float* aw     = (const float*)d_in[5];
    const float* ab     = (const float*)d_in[6];
    const float* weight = (const float*)d_in[7];
    const float* bias   = (const float*)d_in[8];
    float*       out    = (float*)d_out;

    const size_t zoff   = 32768;                               // wmodT at 0, z at 32 KB
    const size_t zbytes = (size_t)N_FACES * NJ * sizeof(unsigned short);

    if (ws_size >= zoff + zbytes) {
        unsigned short* wmodT = (unsigned short*)d_ws;
        unsigned short* z     = (unsigned short*)((char*)d_ws + zoff);

        wmod_bf16_kernel<<<(BATCH * C_IN + 255) / 256, 256, 0, stream>>>(
            w, aw, ab, weight, wmodT);

        // 24576 tiles, 1 wave each, 4 waves/block -> 6144 blocks
        gemm_z_kernel<<<(N_FACES / 16) / 4, 256, 0, stream>>>(x, wmodT, z);

        gather_out_kernel<<<N_FACES / 256, 256, 0, stream>>>(nb, z, bias, out);
    } else {
        float* wmod = (float*)d_ws;  // 48 KB
        wmod_kernel<<<(BATCH * C_IN + 255) / 256, 256, 0, stream>>>(
            w, aw, ab, weight, wmod);
        face_conv_kernel<<<N_FACES / 4, 256, 0, stream>>>(x, nb, wmod, bias, out);
    }
}